// Round 1
// baseline (5527.618 us; speedup 1.0000x reference)
//
#include <hip/hip_runtime.h>
#include <hip/hip_bf16.h>

#define NSWEEP_X 10
#define NSWEEP_W 14
#define LDA 36   // padded column stride (floats): 16B-aligned, bank-spread

__device__ __forceinline__ void wavefence() {
    __builtin_amdgcn_wave_barrier();
    asm volatile("" ::: "memory");
}

// One-sided Jacobi SVD on a 32x32 matrix stored column-major in LDS:
// At[j*LDA + h] = A[h][j]. Accumulates right-rotations into Vt (same layout).
// After convergence: column j of At = u_j * sigma_j ; Vt column j = v_j
// (so Vh row = Vt[j*LDA + w]). One wave (64 lanes) per matrix.
__device__ __forceinline__ void wave_jacobi(float* At, float* Vt, int lane, int nsweep) {
    // init V = I
    for (int e = lane; e < 32 * LDA; e += 64) Vt[e] = 0.0f;
    if (lane < 32) Vt[lane * LDA + lane] = 1.0f;
    wavefence();

    const int g  = lane >> 2;        // pair group 0..15
    const int h0 = (lane & 3) * 8;   // this lane's 8 rows

    for (int sw = 0; sw < nsweep; ++sw) {
        for (int r = 0; r < 31; ++r) {
            // round-robin tournament pairing (player 31 fixed)
            int p = (r + g) % 31;
            int q = (g == 0) ? 31 : (31 - g + r) % 31;

            float ap[8], aq[8];
            float app = 0.0f, aqq = 0.0f, apq = 0.0f;
#pragma unroll
            for (int i = 0; i < 8; i++) {
                ap[i] = At[p * LDA + h0 + i];
                aq[i] = At[q * LDA + h0 + i];
            }
#pragma unroll
            for (int i = 0; i < 8; i++) {
                app = fmaf(ap[i], ap[i], app);
                aqq = fmaf(aq[i], aq[i], aqq);
                apq = fmaf(ap[i], aq[i], apq);
            }
            // reduce across the 4 lanes of this pair-group
            app += __shfl_xor(app, 1); app += __shfl_xor(app, 2);
            aqq += __shfl_xor(aqq, 1); aqq += __shfl_xor(aqq, 2);
            apq += __shfl_xor(apq, 1); apq += __shfl_xor(apq, 2);

            if (apq * apq > 1e-14f * app * aqq) {
                float tau = (aqq - app) / (2.0f * apq);
                float tt  = copysignf(1.0f, tau) / (fabsf(tau) + sqrtf(fmaf(tau, tau, 1.0f)));
                float cth = 1.0f / sqrtf(fmaf(tt, tt, 1.0f));
                float sth = tt * cth;
#pragma unroll
                for (int i = 0; i < 8; i++) {
                    At[p * LDA + h0 + i] = fmaf(cth, ap[i], -sth * aq[i]);
                    At[q * LDA + h0 + i] = fmaf(sth, ap[i],  cth * aq[i]);
                }
#pragma unroll
                for (int i = 0; i < 8; i++) {
                    float vx = Vt[p * LDA + h0 + i];
                    float vy = Vt[q * LDA + h0 + i];
                    Vt[p * LDA + h0 + i] = fmaf(cth, vx, -sth * vy);
                    Vt[q * LDA + h0 + i] = fmaf(sth, vx,  cth * vy);
                }
            }
            wavefence();
        }
    }
}

// Rank columns by squared norm (descending, tie-break by index); modeIdx[m] =
// column index of the m-th largest for m<8.
__device__ __forceinline__ void wave_topk(const float* At, float* nrm, int* modeIdx, int lane) {
    if (lane < 32) {
        float s = 0.0f;
#pragma unroll
        for (int h = 0; h < 32; h++) { float v = At[lane * LDA + h]; s = fmaf(v, v, s); }
        nrm[lane] = s;
    }
    wavefence();
    if (lane < 32) {
        float me = nrm[lane];
        int rk = 0;
        for (int k = 0; k < 32; k++) {
            float o = nrm[k];
            rk += (o > me) || (o == me && k < lane);
        }
        if (rk < 8) modeIdx[rk] = lane;
    }
    wavefence();
}

// ---- Kernel 1: SVD of w[c] (32 matrices). Stores, for each c:
//   uwd[c][h][m] = Uw[h][m]*dw[m]  (= converged column, sigma cancels)
//   vwt[c][w][m] = Vwh[m][w]
__global__ __launch_bounds__(256)
void svd_w_kernel(const float* __restrict__ w, float* __restrict__ uwd, float* __restrict__ vwt) {
    __shared__ float At[4][32 * LDA];
    __shared__ float Vt[4][32 * LDA];
    __shared__ float nrm[4][32];
    __shared__ int   modeIdx[4][8];

    const int t = threadIdx.x, widx = t >> 6, lane = t & 63;
    const int c = blockIdx.x * 4 + widx;

    // load w[c] column-major: At[j][h] = w[c][h][j]
    for (int k = 0; k < 16; k++) {
        int idx = lane + 64 * k;            // idx = h*32 + j
        float v = w[c * 1024 + idx];
        int h = idx >> 5, j = idx & 31;
        At[widx][j * LDA + h] = v;
    }
    wavefence();

    wave_jacobi(At[widx], Vt[widx], lane, NSWEEP_W);
    wave_topk(At[widx], nrm[widx], modeIdx[widx], lane);

    for (int e = lane; e < 256; e += 64) {
        int hh = e >> 3, m = e & 7;
        int j = modeIdx[widx][m];
        uwd[c * 256 + e] = At[widx][j * LDA + hh];
        vwt[c * 256 + e] = Vt[widx][j * LDA + hh];
    }
}

// ---- Kernel 2: per (bt, c): SVD of x[bt][:, :, c], combine with w's SVD,
// write out[bt][h][w][c]. Block = 4 waves = 4 consecutive c of one bt.
// grid: blockIdx = cg*1024 + bt  (same-bt blocks 1024 apart -> same XCD -> L2
// merges the strided 16B accesses into full lines).
__global__ __launch_bounds__(256, 2)
void svd_main_kernel(const float* __restrict__ x, const float* __restrict__ uwd,
                     const float* __restrict__ vwt, float* __restrict__ out) {
    __shared__ float At[4][32 * LDA];
    __shared__ float Vt[4][32 * LDA];
    __shared__ float Pb[4][256];
    __shared__ float Qb[4][256];
    __shared__ float outs[4096];
    __shared__ int   modeIdx[4][8];

    const int t = threadIdx.x, widx = t >> 6, lane = t & 63;
    const int bt = blockIdx.x & 1023, cg = blockIdx.x >> 10;
    const int c = cg * 4 + widx;

    // cooperative load: x[bt][h][wj][cg*4 .. cg*4+3] as float4; component i -> wave i
    const float4* x4 = (const float4*)x;
    const size_t base4 = (size_t)bt * 8192 + (size_t)cg;
#pragma unroll
    for (int k2 = 0; k2 < 4; k2++) {
        int idx = t + 256 * k2;             // idx = h*32 + wj
        float4 v = x4[base4 + (size_t)idx * 8];
        int wj = idx & 31, h = idx >> 5;
        int o = wj * LDA + h;
        At[0][o] = v.x; At[1][o] = v.y; At[2][o] = v.z; At[3][o] = v.w;
    }
    __syncthreads();

    wave_jacobi(At[widx], Vt[widx], lane, NSWEEP_X);
    wave_topk(At[widx], Pb[widx], modeIdx[widx], lane);   // Pb reused as norm buf

    // P[h][m] = (uq*dq)[h,m] * (uw*dw)[h,m] ; Q[w][m] = vq[m,w] * vw[m,w]
    const float* uw = uwd + c * 256;
    const float* vw = vwt + c * 256;
    for (int e = lane; e < 256; e += 64) {
        int hh = e >> 3, m = e & 7;
        int j = modeIdx[widx][m];
        Pb[widx][e] = At[widx][j * LDA + hh] * uw[e];
        Qb[widx][e] = Vt[widx][j * LDA + hh] * vw[e];
    }
    wavefence();

    // out[h][w] = sum_m P[h][m] * Q[w][m]; lane owns w = lane&31, h parity lane>>5
    const int w_ = lane & 31, hpar = lane >> 5;
    float qv[8];
#pragma unroll
    for (int m = 0; m < 8; m++) qv[m] = Qb[widx][w_ * 8 + m];
    for (int k = 0; k < 16; k++) {
        int h = 2 * k + hpar;
        float acc = 0.0f;
#pragma unroll
        for (int m = 0; m < 8; m++) acc = fmaf(Pb[widx][h * 8 + m], qv[m], acc);
        outs[widx * 1024 + h * 32 + w_] = acc;
    }
    __syncthreads();

    // gather 4 c-values per (h,w) -> float4 store to out[bt][h][w][c0..c0+3]
    float4* o4 = (float4*)out;
#pragma unroll
    for (int k2 = 0; k2 < 4; k2++) {
        int idx = t + 256 * k2;
        float4 v = make_float4(outs[idx], outs[1024 + idx], outs[2048 + idx], outs[3072 + idx]);
        o4[base4 + (size_t)idx * 8] = v;
    }
}

extern "C" void kernel_launch(void* const* d_in, const int* in_sizes, int n_in,
                              void* d_out, int out_size, void* d_ws, size_t ws_size,
                              hipStream_t stream) {
    (void)in_sizes; (void)n_in; (void)out_size; (void)ws_size;
    const float* x = (const float*)d_in[0];
    const float* w = (const float*)d_in[1];
    float* out = (float*)d_out;
    float* uwd = (float*)d_ws;            // [32][32][8]
    float* vwt = uwd + 32 * 256;          // [32][32][8]

    hipLaunchKernelGGL(svd_w_kernel, dim3(8), dim3(256), 0, stream, w, uwd, vwt);
    hipLaunchKernelGGL(svd_main_kernel, dim3(8192), dim3(256), 0, stream, x, uwd, vwt, out);
}

// Round 2
// 2336.506 us; speedup vs baseline: 2.3658x; 2.3658x over previous
//
#include <hip/hip_runtime.h>
#include <hip/hip_bf16.h>

#define NSWEEP_X 10
#define NSWEEP_W 14

__device__ __forceinline__ void wavefence() {
    __builtin_amdgcn_wave_barrier();
    asm volatile("" ::: "memory");
}

// One-sided Jacobi on a 32x32 matrix held in registers across one wave.
// lane (j = lane&31, b = lane>>5) holds rows b*16..b*16+15 of column j in a[16].
// XOR ordering: masks m=1..31; pairs {j, j^m} are a perfect matching each round,
// and all 31 masks cover every column pair exactly once per sweep.
// After convergence column j = u_j * sigma_j (sigma cancels downstream).
__device__ __forceinline__ void jacobi_reg(float a[16], int j, int nsweep) {
    for (int sw = 0; sw < nsweep; ++sw) {
        for (int m = 1; m < 32; ++m) {
            float prt[16];
#pragma unroll
            for (int i = 0; i < 16; i++) prt[i] = __shfl_xor(a[i], m);
            float nn = 0.f, cp = 0.f;
#pragma unroll
            for (int i = 0; i < 16; i++) {
                nn = fmaf(a[i], a[i], nn);
                cp = fmaf(a[i], prt[i], cp);
            }
            nn += __shfl_xor(nn, 32);   // full column norm^2 (own column)
            cp += __shfl_xor(cp, 32);   // full dot(own, partner)
            float on = __shfl_xor(nn, m);  // partner column norm^2
            bool isp = j < (j ^ m);
            float app = isp ? nn : on;
            float aqq = isp ? on : nn;
            if (cp * cp > 1e-14f * app * aqq) {
                float tau = (aqq - app) / (2.0f * cp);
                float tt  = copysignf(1.0f, tau) / (fabsf(tau) + sqrtf(fmaf(tau, tau, 1.0f)));
                float cth = 1.0f / sqrtf(fmaf(tt, tt, 1.0f));
                float sth = tt * cth;
                float ss  = isp ? -sth : sth;   // p: c*own - s*other ; q: c*own + s*other
#pragma unroll
                for (int i = 0; i < 16; i++) a[i] = fmaf(ss, prt[i], cth * a[i]);
            }
        }
    }
}

// Rank columns by sigma^2 descending (tie-break by index). Columns with rank<8
// are packed into P0S[rk*33 + h] (h = row), their sigma^2 into sig2S[rk].
__device__ __forceinline__ void rank_and_pack(const float a[16], int j, int b,
                                              float* nrmS, float* P0S, float* sig2S) {
    float nn = 0.f;
#pragma unroll
    for (int i = 0; i < 16; i++) nn = fmaf(a[i], a[i], nn);
    nn += __shfl_xor(nn, 32);
    if (b == 0) nrmS[j] = nn;
    wavefence();
    int rk = 0;
    for (int k = 0; k < 32; k++) {
        float o = nrmS[k];
        rk += (o > nn) || (o == nn && k < j);
    }
    if (rk < 8) {
#pragma unroll
        for (int i = 0; i < 16; i++) P0S[rk * 33 + b * 16 + i] = a[i];
        if (b == 0) sig2S[rk] = nn;
    }
    wavefence();
}

// ---- Kernel 1: SVD of w[c] (32 matrices, one wave per block).
//   uwd[c][h][m] = Uw[h][m]*dw[m]   (converged column)
//   vwt[c][w][m] = Vwh[m][w]        (recovered as A0^T a_m / sigma_m^2)
__global__ __launch_bounds__(64)
void svd_w_kernel(const float* __restrict__ w, float* __restrict__ uwd,
                  float* __restrict__ vwt) {
    __shared__ float P0S[8 * 33];
    __shared__ float nrmS[32];
    __shared__ float sig2S[8];
    const int lane = threadIdx.x, j = lane & 31, b = lane >> 5;
    const int c = blockIdx.x;

    float a[16], a0[16];
#pragma unroll
    for (int i = 0; i < 16; i++) {
        a[i] = w[c * 1024 + (b * 16 + i) * 32 + j];
        a0[i] = a[i];
    }
    jacobi_reg(a, j, NSWEEP_W);
    rank_and_pack(a, j, b, nrmS, P0S, sig2S);

    for (int e = lane; e < 256; e += 64)
        uwd[c * 256 + e] = P0S[(e & 7) * 33 + (e >> 3)];

#pragma unroll
    for (int mm = 0; mm < 8; mm++) {
        float vq = 0.f;
#pragma unroll
        for (int i = 0; i < 16; i++) vq = fmaf(a0[i], P0S[mm * 33 + b * 16 + i], vq);
        vq += __shfl_xor(vq, 32);
        vq /= sig2S[mm];
        if (b == 0) vwt[c * 256 + j * 8 + mm] = vq;
    }
}

// ---- Kernel 2: per (bt, c): register Jacobi SVD of x[bt][:,:,c], combine with
// w's SVD, write out[bt][h][w][c]. Block = 4 waves = 4 consecutive c of one bt.
__global__ __launch_bounds__(256, 5)
void svd_main_kernel(const float* __restrict__ x, const float* __restrict__ uwd,
                     const float* __restrict__ vwt, float* __restrict__ out) {
    __shared__ float SB[4][1056];      // stage-in [wj*33+h]; reused as outs [h*32+wj]
    __shared__ float P0S[4][8 * 33];
    __shared__ float PgS[4][256];
    __shared__ float nrmS[4][32];
    __shared__ float sig2S[4][8];

    const int t = threadIdx.x, widx = t >> 6, lane = t & 63;
    const int j = lane & 31, b = lane >> 5;
    const int bt = blockIdx.x & 1023, cg = blockIdx.x >> 10;
    const int c = cg * 4 + widx;

    // cooperative float4 load over c-minor layout; component i -> wave i's region
    const float4* x4 = (const float4*)x;
    const size_t base4 = (size_t)bt * 8192 + (size_t)cg;
#pragma unroll
    for (int k2 = 0; k2 < 4; k2++) {
        int idx = t + 256 * k2;              // idx = h*32 + wj
        float4 v = x4[base4 + (size_t)idx * 8];
        int wj = idx & 31, h = idx >> 5;
        int o = wj * 33 + h;
        SB[0][o] = v.x; SB[1][o] = v.y; SB[2][o] = v.z; SB[3][o] = v.w;
    }
    __syncthreads();

    float a[16], a0[16];
#pragma unroll
    for (int i = 0; i < 16; i++) {
        a[i] = SB[widx][j * 33 + b * 16 + i];
        a0[i] = a[i];
    }
    wavefence();

    jacobi_reg(a, j, NSWEEP_X);
    rank_and_pack(a, j, b, nrmS[widx], P0S[widx], sig2S[widx]);

    // Q[j][mm] = (A0^T a_mm / sigma^2) * vw  -> kept in registers
    const float* vw = vwt + c * 256;
    float qv[8];
#pragma unroll
    for (int mm = 0; mm < 8; mm++) {
        float vq = 0.f;
#pragma unroll
        for (int i = 0; i < 16; i++) vq = fmaf(a0[i], P0S[widx][mm * 33 + b * 16 + i], vq);
        vq += __shfl_xor(vq, 32);
        vq /= sig2S[widx][mm];
        qv[mm] = vq * vw[j * 8 + mm];
    }

    // Pg[h][mm] = (uq*dq)[h,mm] * (uw*dw)[h,mm]
    const float* uw = uwd + c * 256;
    for (int e = lane; e < 256; e += 64)
        PgS[widx][e] = P0S[widx][(e & 7) * 33 + (e >> 3)] * uw[e];
    wavefence();

    // out[h][j] = sum_mm Pg[h][mm] * qv[mm]; lane covers h = b*16..b*16+15
#pragma unroll
    for (int i = 0; i < 16; i++) {
        int h = b * 16 + i;
        float acc = 0.f;
#pragma unroll
        for (int mm = 0; mm < 8; mm++) acc = fmaf(PgS[widx][h * 8 + mm], qv[mm], acc);
        SB[widx][h * 32 + j] = acc;
    }
    __syncthreads();

    // gather 4 c-values per (h,w) -> float4 store to out[bt][h][w][c0..c0+3]
    float4* o4 = (float4*)out;
#pragma unroll
    for (int k2 = 0; k2 < 4; k2++) {
        int idx = t + 256 * k2;
        float4 v = make_float4(SB[0][idx], SB[1][idx], SB[2][idx], SB[3][idx]);
        o4[base4 + (size_t)idx * 8] = v;
    }
}

extern "C" void kernel_launch(void* const* d_in, const int* in_sizes, int n_in,
                              void* d_out, int out_size, void* d_ws, size_t ws_size,
                              hipStream_t stream) {
    (void)in_sizes; (void)n_in; (void)out_size; (void)ws_size;
    const float* x = (const float*)d_in[0];
    const float* w = (const float*)d_in[1];
    float* out = (float*)d_out;
    float* uwd = (float*)d_ws;            // [32][32][8]
    float* vwt = uwd + 32 * 256;          // [32][32][8]

    hipLaunchKernelGGL(svd_w_kernel, dim3(32), dim3(64), 0, stream, w, uwd, vwt);
    hipLaunchKernelGGL(svd_main_kernel, dim3(8192), dim3(256), 0, stream, x, uwd, vwt, out);
}